// Round 5
// baseline (206.259 us; speedup 1.0000x reference)
//
#include <hip/hip_runtime.h>
#include <math.h>
#include <stdint.h>

#define B_   4
#define C_   256
#define H_   64
#define W_   64
#define CC_  64
#define OE_  196
#define OH_  128
#define OW_  128

typedef uint32_t u32;
typedef __attribute__((ext_vector_type(8))) short bf16x8;
typedef __attribute__((ext_vector_type(4))) float f32x4;
typedef __attribute__((ext_vector_type(4))) u32 u32x4;
typedef __attribute__((ext_vector_type(2))) u32 u32x2;

__device__ __forceinline__ unsigned short f2bf(float f) {
  u32 u = __builtin_bit_cast(u32, f);
  u32 r = (u + 0x7FFFu + ((u >> 16) & 1u)) >> 16;   // RNE
  return (unsigned short)r;
}

// ------------------------------------------------------------------
// Kernel 0: weight re-layouts (tiny).
// ------------------------------------------------------------------
__global__ __launch_bounds__(256) void prep_weights(
    const float* __restrict__ w_comp, const float* __restrict__ w_enc,
    float* __restrict__ wct, unsigned short* __restrict__ wfrag) {
  int idx = blockIdx.x * 256 + threadIdx.x;
  if (idx < 50 * 14 * 64) {
    int lane = idx & 63;
    int mt   = (idx >> 6) % 14;
    int ks   = idx / (14 * 64);
    int o    = mt * 16 + (lane & 15);
    int tap  = ks >> 1, s = ks & 1;
    int ky   = tap / 5, kx = tap % 5;
    int cb   = s * 32 + (lane >> 4) * 8;
    u32 pk[4];
    #pragma unroll
    for (int p = 0; p < 4; ++p) {
      unsigned short lo = 0, hi = 0;
      if (o < OE_) {
        lo = f2bf(w_enc[((o * CC_ + cb + 2 * p) * 5 + ky) * 5 + kx]);
        hi = f2bf(w_enc[((o * CC_ + cb + 2 * p + 1) * 5 + ky) * 5 + kx]);
      }
      pk[p] = (u32)lo | ((u32)hi << 16);
    }
    *reinterpret_cast<u32x4*>(wfrag + (size_t)idx * 8) =
        *reinterpret_cast<u32x4*>(pk);
  }
  if (idx < C_ * CC_) {
    int cc = idx / C_, c = idx % C_;
    wct[c * CC_ + cc] = w_comp[cc * C_ + c];
  }
}

// ------------------------------------------------------------------
// Kernel 1: 1x1 compressor v3 — 16-w blocks, grid 1024 (4 blocks/CU),
// LDS 20KB (8 blocks/CU capacity).  Emits bf16 comp[b][h][w][cc] and
// fp32 channels-last xt[b][h][w][c].
// ------------------------------------------------------------------
__global__ __launch_bounds__(256) void compress_k(
    const float* __restrict__ x, const float* __restrict__ wct,
    const float* __restrict__ b_comp, unsigned short* __restrict__ comp,
    float* __restrict__ xt) {
  __shared__ float xs[C_ * 20];   // 20,480B; stride 20 (16B-aligned rows)
  int t   = threadIdx.x;
  int gid = blockIdx.x;           // bh*4 + wq
  int wq  = gid & 3;
  int bh  = gid >> 2;
  int b = bh >> 6, h = bh & 63;
  int w0 = wq * 16;

  const float* xrow = x + (size_t)b * C_ * H_ * W_ + (size_t)h * W_ + w0;
  for (int i = t; i < 1024; i += 256) {    // 256 c x 4 f32x4
    int c = i >> 2, q = i & 3;
    f32x4 v = *reinterpret_cast<const f32x4*>(xrow + (size_t)c * H_ * W_ + q * 4);
    *reinterpret_cast<f32x4*>(xs + c * 20 + q * 4) = v;
  }
  __syncthreads();

  int w = t & 15, cq = t >> 4;   // cq 0..15

  // --- xt write: thread (w, cq) covers channels cq*16..cq*16+15 ---
  {
    float* dst = xt + ((size_t)bh * 64 + w0 + w) * C_ + cq * 16;
    #pragma unroll
    for (int i = 0; i < 4; ++i) {
      int c = cq * 16 + i * 4;
      f32x4 v = {xs[c * 20 + w], xs[(c + 1) * 20 + w],
                 xs[(c + 2) * 20 + w], xs[(c + 3) * 20 + w]};
      *reinterpret_cast<f32x4*>(dst + i * 4) = v;
    }
  }

  // --- 1x1 conv: thread (w, ccg=cq) -> 4 cc ---
  float acc[4] = {0.f, 0.f, 0.f, 0.f};
  for (int c = 0; c < C_; ++c) {
    float xv = xs[c * 20 + w];
    const float* wr = wct + c * CC_ + cq * 4;
    #pragma unroll
    for (int i = 0; i < 4; ++i) acc[i] = fmaf(xv, wr[i], acc[i]);
  }
  u32 pk[2];
  #pragma unroll
  for (int p = 0; p < 2; ++p) {
    unsigned short lo = f2bf(acc[2 * p]     + b_comp[cq * 4 + 2 * p]);
    unsigned short hi = f2bf(acc[2 * p + 1] + b_comp[cq * 4 + 2 * p + 1]);
    pk[p] = (u32)lo | ((u32)hi << 16);
  }
  *reinterpret_cast<u32x2*>(comp + ((size_t)bh * 64 + w0 + w) * CC_ + cq * 4) =
      *reinterpret_cast<u32x2*>(pk);
}

// ------------------------------------------------------------------
// Kernel 2: encoder 5x5 conv as MFMA GEMM + fused softmax (unchanged).
// smax layout [pixel][n(49)][r(4)].
// ------------------------------------------------------------------
#define WB_ 14336
#define CSB_ 43520
__global__ __launch_bounds__(256) void enc_mfma_k(
    const unsigned short* __restrict__ comp,
    const unsigned short* __restrict__ wfrag,
    const float* __restrict__ b_enc,
    float* __restrict__ smax) {
  __shared__ __align__(16) char lds[CSB_ + 2 * WB_];   // 72192 B
  char* wbuf0 = lds + CSB_;
  char* wbuf1 = lds + CSB_ + WB_;

  int t = threadIdx.x;
  int bh = blockIdx.x;
  int b = bh >> 6, h = bh & 63;

  {
    u32x4 z = {0, 0, 0, 0};
    for (int i = t; i < 160; i += 256) {
      int r = i / 32, rem = i & 31, ch = rem >> 3, q = rem & 7;
      int col = (ch < 2) ? ch : 64 + ch;
      int byte = ((r * 68 + col) * 128 + q * 16) ^ ((col & 7) << 4);
      *reinterpret_cast<u32x4*>(lds + byte) = z;
    }
    const unsigned short* cbse = comp + (size_t)b * H_ * W_ * CC_;
    for (int i = t; i < 2560; i += 256) {
      int r = i >> 9, rem = i & 511, w = rem >> 3, q = rem & 7;
      int hh = h - 2 + r;
      u32x4 v = {0, 0, 0, 0};
      if ((unsigned)hh < H_)
        v = *reinterpret_cast<const u32x4*>(cbse + ((size_t)hh * W_ + w) * CC_ + q * 8);
      int col = w + 2;
      int byte = ((r * 68 + col) * 128 + q * 16) ^ ((col & 7) << 4);
      *reinterpret_cast<u32x4*>(lds + byte) = v;
    }
  }

  int wv    = __builtin_amdgcn_readfirstlane(t >> 6);
  int lane  = t & 63;
  int nlane = lane & 15, kq = lane >> 4;
  int mtbase = (wv < 2) ? wv * 4 : 3 * wv + 2;   // {0,4,8,11}
  int mtcnt  = (wv < 2) ? 4 : 3;

  #define STAGE_W(ks, dstbuf)                                                 \
    {                                                                         \
      const char* _s = (const char*)wfrag + (size_t)(ks) * WB_;               \
      for (int _i = wv; _i < 14; _i += 4)                                     \
        __builtin_amdgcn_global_load_lds(                                     \
            (const __attribute__((address_space(1))) u32*)(_s + _i * 1024 +   \
                                                           lane * 16),        \
            (__attribute__((address_space(3))) u32*)((dstbuf) + _i * 1024),   \
            16, 0, 0);                                                        \
    }

  STAGE_W(0, wbuf0);
  __syncthreads();

  f32x4 acc[4][4];
  #pragma unroll
  for (int mm = 0; mm < 4; ++mm)
    #pragma unroll
    for (int nt = 0; nt < 4; ++nt) acc[mm][nt] = (f32x4){0.f, 0.f, 0.f, 0.f};

  for (int ks = 0; ks < 50; ++ks) {
    char* cur = (ks & 1) ? wbuf1 : wbuf0;
    char* nxt = (ks & 1) ? wbuf0 : wbuf1;
    if (ks + 1 < 50) STAGE_W(ks + 1, nxt);

    int tap = ks >> 1, s = ks & 1;
    int ky = tap / 5, kx = tap % 5;

    bf16x8 bf[4];
    #pragma unroll
    for (int nt = 0; nt < 4; ++nt) {
      int col = nt * 16 + nlane + kx;
      int byte = (((ky * 68 + col) * 64 + s * 32 + kq * 8) * 2) ^ ((col & 7) << 4);
      bf[nt] = *reinterpret_cast<const bf16x8*>(lds + byte);
    }
    #pragma unroll
    for (int mm = 0; mm < 4; ++mm) {
      if (mm < mtcnt) {
        bf16x8 af = *reinterpret_cast<const bf16x8*>(
            cur + ((mtbase + mm) * 64 + lane) * 16);
        #pragma unroll
        for (int nt = 0; nt < 4; ++nt)
          acc[mm][nt] = __builtin_amdgcn_mfma_f32_16x16x32_bf16(
              af, bf[nt], acc[mm][nt], 0, 0, 0);
      }
    }
    __syncthreads();
  }

  float* lg = (float*)lds;
  #pragma unroll
  for (int mm = 0; mm < 4; ++mm) {
    if (mm < mtcnt) {
      #pragma unroll
      for (int nt = 0; nt < 4; ++nt) {
        #pragma unroll
        for (int r = 0; r < 4; ++r) {
          int m  = (mtbase + mm) * 16 + kq * 4 + r;
          int px = nt * 16 + nlane;
          lg[m * 68 + px] = acc[mm][nt][r] + (m < OE_ ? b_enc[m] : 0.f);
        }
      }
    }
  }
  __syncthreads();

  int px = t & 63, rr = t >> 6;
  float v[49];
  float mx = -1e30f;
  #pragma unroll
  for (int n = 0; n < 49; ++n) {
    v[n] = lg[(4 * n + rr) * 68 + px];
    mx = fmaxf(mx, v[n]);
  }
  float sum = 0.f;
  #pragma unroll
  for (int n = 0; n < 49; ++n) { v[n] = __expf(v[n] - mx); sum += v[n]; }
  float inv = 1.f / sum;
  float* so = smax + ((size_t)bh * 64 + px) * OE_;
  #pragma unroll
  for (int n = 0; n < 49; ++n) so[n * 4 + rr] = v[n] * inv;   // [n][r] layout
}

// ------------------------------------------------------------------
// Kernel 3: CARAFE v4 — occupancy build.  16-channel blocks, LDS
// 19.2KB -> 8 blocks/CU (32 waves/CU).  Per thread: 2 ch x 4 r;
// per tap: 1 global b128 (sv) + 1 LDS b64 (xv) + 8 FMA.
// xs stride 18 dwords: b64 reads conflict-free, 8B-aligned.
// ------------------------------------------------------------------
__global__ __launch_bounds__(256, 8) void carafe_k(
    const float* __restrict__ xt, const float* __restrict__ smax,
    float* __restrict__ out) {
  __shared__ __align__(16) float xs[7 * 38 * 18];   // 19,152B
  int t   = threadIdx.x;
  int gid = blockIdx.x;
  int cg  = gid & 15;          // 16-channel group
  int wh  = (gid >> 4) & 1;    // w half
  int bh  = gid >> 5;          // b*64 + h
  int b = bh >> 6, h = bh & 63;
  int c0 = cg * 16, w0 = wh * 32;

  // ---- stage x tile: 7 rows x 38 cols x 16 ch, float2 units ----
  for (int idx = t; idx < 2128; idx += 256) {
    int q  = idx & 7;               // channel pair 0..7
    int rj = idx >> 3;              // dy*38 + j
    int j  = rj % 38, dy = rj / 38;
    int gh = h - 3 + dy, gw = w0 - 3 + j;
    float2 v = make_float2(0.f, 0.f);
    if ((unsigned)gh < H_ && (unsigned)gw < W_)
      v = *reinterpret_cast<const float2*>(
          xt + (((size_t)(b * 64 + gh)) * 64 + gw) * C_ + c0 + q * 2);
    *reinterpret_cast<float2*>(xs + rj * 18 + q * 2) = v;
  }
  __syncthreads();

  int w = t & 31, cq = t >> 5;   // cq 0..7 -> 2 channels
  const float* sp = smax + ((size_t)bh * 64 + w0 + w) * OE_;
  f32x4 acc0 = {0.f, 0.f, 0.f, 0.f};   // channel c0+cq*2
  f32x4 acc1 = {0.f, 0.f, 0.f, 0.f};   // channel c0+cq*2+1

  #pragma unroll
  for (int dy = 0; dy < 7; ++dy) {
    #pragma unroll
    for (int dx = 0; dx < 7; ++dx) {
      int n = dy * 7 + dx;
      f32x4 sv = *reinterpret_cast<const f32x4*>(sp + n * 4);
      float2 xv = *reinterpret_cast<const float2*>(
          xs + (dy * 38 + w + dx) * 18 + cq * 2);
      acc0[0] = fmaf(xv.x, sv[0], acc0[0]);
      acc0[1] = fmaf(xv.x, sv[1], acc0[1]);
      acc0[2] = fmaf(xv.x, sv[2], acc0[2]);
      acc0[3] = fmaf(xv.x, sv[3], acc0[3]);
      acc1[0] = fmaf(xv.y, sv[0], acc1[0]);
      acc1[1] = fmaf(xv.y, sv[1], acc1[1]);
      acc1[2] = fmaf(xv.y, sv[2], acc1[2]);
      acc1[3] = fmaf(xv.y, sv[3], acc1[3]);
    }
  }

  int c = c0 + cq * 2;
  float* base0 = out + ((size_t)(b * C_ + c) * OH_ + 2 * h) * OW_ + 2 * (w0 + w);
  *reinterpret_cast<float2*>(base0)        = make_float2(acc0[0], acc0[1]);
  *reinterpret_cast<float2*>(base0 + OW_)  = make_float2(acc0[2], acc0[3]);
  float* base1 = base0 + (size_t)OH_ * OW_;
  *reinterpret_cast<float2*>(base1)        = make_float2(acc1[0], acc1[1]);
  *reinterpret_cast<float2*>(base1 + OW_)  = make_float2(acc1[2], acc1[3]);
}

// ------------------------------------------------------------------
extern "C" void kernel_launch(void* const* d_in, const int* in_sizes, int n_in,
                              void* d_out, int out_size, void* d_ws, size_t ws_size,
                              hipStream_t stream) {
  const float* x      = (const float*)d_in[0];
  const float* w_comp = (const float*)d_in[1];
  const float* b_comp = (const float*)d_in[2];
  const float* w_enc  = (const float*)d_in[3];
  const float* b_enc  = (const float*)d_in[4];
  float* out = (float*)d_out;

  float* ws = (float*)d_ws;
  float* smax = ws;                                        // 3,211,264 f32
  float* wct  = ws + 3211264;                              //    16,384 f32
  unsigned short* wfrag = (unsigned short*)(wct + 16384);  //   358,400 bf16
  unsigned short* comp  = wfrag + 358400;                  // 1,048,576 bf16
  float* xt = (float*)(comp + 1048576);                    // 4,194,304 f32 (~32.5MB total)

  prep_weights<<<175, 256, 0, stream>>>(w_comp, w_enc, wct, wfrag);
  compress_k<<<B_ * H_ * 4, 256, 0, stream>>>(x, wct, b_comp, comp, xt);
  enc_mfma_k<<<B_ * H_, 256, 0, stream>>>(comp, wfrag, b_enc, smax);
  carafe_k<<<B_ * H_ * 2 * 16, 256, 0, stream>>>(xt, smax, out);
}

// Round 6
// 168.955 us; speedup vs baseline: 1.2208x; 1.2208x over previous
//
#include <hip/hip_runtime.h>
#include <math.h>
#include <stdint.h>

#define B_   4
#define C_   256
#define H_   64
#define W_   64
#define CC_  64
#define OE_  196
#define OH_  128
#define OW_  128

typedef uint32_t u32;
typedef __attribute__((ext_vector_type(8))) short bf16x8;
typedef __attribute__((ext_vector_type(4))) float f32x4;
typedef __attribute__((ext_vector_type(4))) u32 u32x4;
typedef __attribute__((ext_vector_type(2))) u32 u32x2;

__device__ __forceinline__ unsigned short f2bf(float f) {
  u32 u = __builtin_bit_cast(u32, f);
  u32 r = (u + 0x7FFFu + ((u >> 16) & 1u)) >> 16;   // RNE
  return (unsigned short)r;
}

// ------------------------------------------------------------------
// Kernel 0: weight re-layouts (tiny).
// ------------------------------------------------------------------
__global__ __launch_bounds__(256) void prep_weights(
    const float* __restrict__ w_comp, const float* __restrict__ w_enc,
    float* __restrict__ wct, unsigned short* __restrict__ wfrag) {
  int idx = blockIdx.x * 256 + threadIdx.x;
  if (idx < 50 * 14 * 64) {
    int lane = idx & 63;
    int mt   = (idx >> 6) % 14;
    int ks   = idx / (14 * 64);
    int o    = mt * 16 + (lane & 15);
    int tap  = ks >> 1, s = ks & 1;
    int ky   = tap / 5, kx = tap % 5;
    int cb   = s * 32 + (lane >> 4) * 8;
    u32 pk[4];
    #pragma unroll
    for (int p = 0; p < 4; ++p) {
      unsigned short lo = 0, hi = 0;
      if (o < OE_) {
        lo = f2bf(w_enc[((o * CC_ + cb + 2 * p) * 5 + ky) * 5 + kx]);
        hi = f2bf(w_enc[((o * CC_ + cb + 2 * p + 1) * 5 + ky) * 5 + kx]);
      }
      pk[p] = (u32)lo | ((u32)hi << 16);
    }
    *reinterpret_cast<u32x4*>(wfrag + (size_t)idx * 8) =
        *reinterpret_cast<u32x4*>(pk);
  }
  if (idx < C_ * CC_) {
    int cc = idx / C_, c = idx % C_;
    wct[c * CC_ + cc] = w_comp[cc * C_ + c];
  }
}

// ------------------------------------------------------------------
// Kernel 1: 1x1 compressor — 16-w blocks, grid 1024, LDS 20KB.
// No xt side-output (carafe now reads x directly).
// ------------------------------------------------------------------
__global__ __launch_bounds__(256) void compress_k(
    const float* __restrict__ x, const float* __restrict__ wct,
    const float* __restrict__ b_comp, unsigned short* __restrict__ comp) {
  __shared__ float xs[C_ * 20];   // 20,480B
  int t   = threadIdx.x;
  int gid = blockIdx.x;           // bh*4 + wq
  int wq  = gid & 3;
  int bh  = gid >> 2;
  int b = bh >> 6, h = bh & 63;
  int w0 = wq * 16;

  const float* xrow = x + (size_t)b * C_ * H_ * W_ + (size_t)h * W_ + w0;
  for (int i = t; i < 1024; i += 256) {    // 256 c x 4 f32x4
    int c = i >> 2, q = i & 3;
    f32x4 v = *reinterpret_cast<const f32x4*>(xrow + (size_t)c * H_ * W_ + q * 4);
    *reinterpret_cast<f32x4*>(xs + c * 20 + q * 4) = v;
  }
  __syncthreads();

  int w = t & 15, cq = t >> 4;   // cq 0..15 -> 4 cc each
  float acc[4] = {0.f, 0.f, 0.f, 0.f};
  for (int c = 0; c < C_; ++c) {
    float xv = xs[c * 20 + w];
    const float* wr = wct + c * CC_ + cq * 4;
    #pragma unroll
    for (int i = 0; i < 4; ++i) acc[i] = fmaf(xv, wr[i], acc[i]);
  }
  u32 pk[2];
  #pragma unroll
  for (int p = 0; p < 2; ++p) {
    unsigned short lo = f2bf(acc[2 * p]     + b_comp[cq * 4 + 2 * p]);
    unsigned short hi = f2bf(acc[2 * p + 1] + b_comp[cq * 4 + 2 * p + 1]);
    pk[p] = (u32)lo | ((u32)hi << 16);
  }
  *reinterpret_cast<u32x2*>(comp + ((size_t)bh * 64 + w0 + w) * CC_ + cq * 4) =
      *reinterpret_cast<u32x2*>(pk);
}

// ------------------------------------------------------------------
// Kernel 2: encoder 5x5 conv as MFMA GEMM + fused softmax (unchanged).
// smax layout [pixel][n(49)][r(4)].
// ------------------------------------------------------------------
#define WB_ 14336
#define CSB_ 43520
__global__ __launch_bounds__(256) void enc_mfma_k(
    const unsigned short* __restrict__ comp,
    const unsigned short* __restrict__ wfrag,
    const float* __restrict__ b_enc,
    float* __restrict__ smax) {
  __shared__ __align__(16) char lds[CSB_ + 2 * WB_];   // 72192 B
  char* wbuf0 = lds + CSB_;
  char* wbuf1 = lds + CSB_ + WB_;

  int t = threadIdx.x;
  int bh = blockIdx.x;
  int b = bh >> 6, h = bh & 63;

  {
    u32x4 z = {0, 0, 0, 0};
    for (int i = t; i < 160; i += 256) {
      int r = i / 32, rem = i & 31, ch = rem >> 3, q = rem & 7;
      int col = (ch < 2) ? ch : 64 + ch;
      int byte = ((r * 68 + col) * 128 + q * 16) ^ ((col & 7) << 4);
      *reinterpret_cast<u32x4*>(lds + byte) = z;
    }
    const unsigned short* cbse = comp + (size_t)b * H_ * W_ * CC_;
    for (int i = t; i < 2560; i += 256) {
      int r = i >> 9, rem = i & 511, w = rem >> 3, q = rem & 7;
      int hh = h - 2 + r;
      u32x4 v = {0, 0, 0, 0};
      if ((unsigned)hh < H_)
        v = *reinterpret_cast<const u32x4*>(cbse + ((size_t)hh * W_ + w) * CC_ + q * 8);
      int col = w + 2;
      int byte = ((r * 68 + col) * 128 + q * 16) ^ ((col & 7) << 4);
      *reinterpret_cast<u32x4*>(lds + byte) = v;
    }
  }

  int wv    = __builtin_amdgcn_readfirstlane(t >> 6);
  int lane  = t & 63;
  int nlane = lane & 15, kq = lane >> 4;
  int mtbase = (wv < 2) ? wv * 4 : 3 * wv + 2;   // {0,4,8,11}
  int mtcnt  = (wv < 2) ? 4 : 3;

  #define STAGE_W(ks, dstbuf)                                                 \
    {                                                                         \
      const char* _s = (const char*)wfrag + (size_t)(ks) * WB_;               \
      for (int _i = wv; _i < 14; _i += 4)                                     \
        __builtin_amdgcn_global_load_lds(                                     \
            (const __attribute__((address_space(1))) u32*)(_s + _i * 1024 +   \
                                                           lane * 16),        \
            (__attribute__((address_space(3))) u32*)((dstbuf) + _i * 1024),   \
            16, 0, 0);                                                        \
    }

  STAGE_W(0, wbuf0);
  __syncthreads();

  f32x4 acc[4][4];
  #pragma unroll
  for (int mm = 0; mm < 4; ++mm)
    #pragma unroll
    for (int nt = 0; nt < 4; ++nt) acc[mm][nt] = (f32x4){0.f, 0.f, 0.f, 0.f};

  for (int ks = 0; ks < 50; ++ks) {
    char* cur = (ks & 1) ? wbuf1 : wbuf0;
    char* nxt = (ks & 1) ? wbuf0 : wbuf1;
    if (ks + 1 < 50) STAGE_W(ks + 1, nxt);

    int tap = ks >> 1, s = ks & 1;
    int ky = tap / 5, kx = tap % 5;

    bf16x8 bf[4];
    #pragma unroll
    for (int nt = 0; nt < 4; ++nt) {
      int col = nt * 16 + nlane + kx;
      int byte = (((ky * 68 + col) * 64 + s * 32 + kq * 8) * 2) ^ ((col & 7) << 4);
      bf[nt] = *reinterpret_cast<const bf16x8*>(lds + byte);
    }
    #pragma unroll
    for (int mm = 0; mm < 4; ++mm) {
      if (mm < mtcnt) {
        bf16x8 af = *reinterpret_cast<const bf16x8*>(
            cur + ((mtbase + mm) * 64 + lane) * 16);
        #pragma unroll
        for (int nt = 0; nt < 4; ++nt)
          acc[mm][nt] = __builtin_amdgcn_mfma_f32_16x16x32_bf16(
              af, bf[nt], acc[mm][nt], 0, 0, 0);
      }
    }
    __syncthreads();
  }

  float* lg = (float*)lds;
  #pragma unroll
  for (int mm = 0; mm < 4; ++mm) {
    if (mm < mtcnt) {
      #pragma unroll
      for (int nt = 0; nt < 4; ++nt) {
        #pragma unroll
        for (int r = 0; r < 4; ++r) {
          int m  = (mtbase + mm) * 16 + kq * 4 + r;
          int px = nt * 16 + nlane;
          lg[m * 68 + px] = acc[mm][nt][r] + (m < OE_ ? b_enc[m] : 0.f);
        }
      }
    }
  }
  __syncthreads();

  int px = t & 63, rr = t >> 6;
  float v[49];
  float mx = -1e30f;
  #pragma unroll
  for (int n = 0; n < 49; ++n) {
    v[n] = lg[(4 * n + rr) * 68 + px];
    mx = fmaxf(mx, v[n]);
  }
  float sum = 0.f;
  #pragma unroll
  for (int n = 0; n < 49; ++n) { v[n] = __expf(v[n] - mx); sum += v[n]; }
  float inv = 1.f / sum;
  float* so = smax + ((size_t)bh * 64 + px) * OE_;
  #pragma unroll
  for (int n = 0; n < 49; ++n) so[n * 4 + rr] = v[n] * inv;   // [n][r] layout
}

// ------------------------------------------------------------------
// Kernel 3: CARAFE v5 — reads x DIRECTLY (no xt).  32ch x 32w blocks,
// LDS xs[c][dy][j'] stride 308/44 (skewed, <=2-way bank alias).
// sv from global with 7-deep dy-pipelined register prefetch.
// launch_bounds(256,4): VGPR cap 128 -> MLP preserved, 16 waves/CU.
// XCD-chunked swizzle: 8 cg-blocks + 32 rows share one XCD L2.
// ------------------------------------------------------------------
__global__ __launch_bounds__(256, 4) void carafe_k(
    const float* __restrict__ x, const float* __restrict__ smax,
    float* __restrict__ out) {
  __shared__ __align__(16) float xs[32 * 308];   // 39,424 B
  int t   = threadIdx.x;
  int bid = blockIdx.x;
  int swz = (bid & 7) * 512 + (bid >> 3);   // 4096 blocks, bijective
  int cg  = swz & 7;
  int wh  = (swz >> 3) & 1;
  int bh  = swz >> 4;
  int b = bh >> 6, h = bh & 63;
  int c0 = cg * 32, w0 = wh * 32;

  // ---- stage x tile: 32 ch x 7 rows x 44 cols (11 f32x4 per row) ----
  const float* xb = x + (size_t)(b * C_ + c0) * H_ * W_;
  for (int idx = t; idx < 2464; idx += 256) {
    int c = idx / 77, rem = idx % 77;
    int dy = rem / 11, q = rem - dy * 11;
    int gh = h - 3 + dy, gw0 = w0 - 4 + q * 4;
    f32x4 v = {0.f, 0.f, 0.f, 0.f};
    if ((unsigned)gh < H_ && (unsigned)gw0 < 61)   // whole vec in [0,64)
      v = *reinterpret_cast<const f32x4*>(xb + (size_t)c * H_ * W_ + gh * W_ + gw0);
    *reinterpret_cast<f32x4*>(xs + c * 308 + dy * 44 + q * 4) = v;
  }
  __syncthreads();

  int w = t & 31, cq = t >> 5;   // cq 0..7 -> 4 channels
  const float* sp = smax + ((size_t)bh * 64 + w0 + w) * OE_;
  f32x4 acc[4];
  #pragma unroll
  for (int ci = 0; ci < 4; ++ci) acc[ci] = (f32x4){0.f, 0.f, 0.f, 0.f};

  // 7-deep register pipeline: prefetch dy+1's 7 sv while FMAing dy.
  f32x4 svA[7], svB[7];
  #pragma unroll
  for (int n = 0; n < 7; ++n)
    svA[n] = *reinterpret_cast<const f32x4*>(sp + n * 4);

  #pragma unroll
  for (int dy = 0; dy < 7; ++dy) {
    if (dy < 6) {
      #pragma unroll
      for (int n = 0; n < 7; ++n) {
        f32x4 v = *reinterpret_cast<const f32x4*>(sp + ((dy + 1) * 7 + n) * 4);
        if (dy & 1) svA[n] = v; else svB[n] = v;   // static after unroll
      }
    }
    #pragma unroll
    for (int dx = 0; dx < 7; ++dx) {
      f32x4 sv = (dy & 1) ? svB[dx] : svA[dx];
      int jj = dy * 44 + w + dx + 1;
      #pragma unroll
      for (int ci = 0; ci < 4; ++ci) {
        float xv = xs[(cq * 4 + ci) * 308 + jj];
        acc[ci][0] = fmaf(xv, sv[0], acc[ci][0]);
        acc[ci][1] = fmaf(xv, sv[1], acc[ci][1]);
        acc[ci][2] = fmaf(xv, sv[2], acc[ci][2]);
        acc[ci][3] = fmaf(xv, sv[3], acc[ci][3]);
      }
    }
  }

  #pragma unroll
  for (int ci = 0; ci < 4; ++ci) {
    int c = c0 + cq * 4 + ci;
    float* base = out + ((size_t)(b * C_ + c) * OH_ + 2 * h) * OW_ + 2 * (w0 + w);
    *reinterpret_cast<float2*>(base)       = make_float2(acc[ci][0], acc[ci][1]);
    *reinterpret_cast<float2*>(base + OW_) = make_float2(acc[ci][2], acc[ci][3]);
  }
}

// ------------------------------------------------------------------
extern "C" void kernel_launch(void* const* d_in, const int* in_sizes, int n_in,
                              void* d_out, int out_size, void* d_ws, size_t ws_size,
                              hipStream_t stream) {
  const float* x      = (const float*)d_in[0];
  const float* w_comp = (const float*)d_in[1];
  const float* b_comp = (const float*)d_in[2];
  const float* w_enc  = (const float*)d_in[3];
  const float* b_enc  = (const float*)d_in[4];
  float* out = (float*)d_out;

  float* ws = (float*)d_ws;
  float* smax = ws;                                        // 3,211,264 f32
  float* wct  = ws + 3211264;                              //    16,384 f32
  unsigned short* wfrag = (unsigned short*)(wct + 16384);  //   358,400 bf16
  unsigned short* comp  = wfrag + 358400;                  // 1,048,576 bf16

  prep_weights<<<175, 256, 0, stream>>>(w_comp, w_enc, wct, wfrag);
  compress_k<<<B_ * H_ * 4, 256, 0, stream>>>(x, wct, b_comp, comp);
  enc_mfma_k<<<B_ * H_, 256, 0, stream>>>(comp, wfrag, b_enc, smax);
  carafe_k<<<B_ * H_ * 2 * 8, 256, 0, stream>>>(x, smax, out);
}

// Round 7
// 156.396 us; speedup vs baseline: 1.3188x; 1.0803x over previous
//
#include <hip/hip_runtime.h>
#include <math.h>
#include <stdint.h>

#define B_   4
#define C_   256
#define H_   64
#define W_   64
#define CC_  64
#define OE_  196
#define OH_  128
#define OW_  128

typedef uint32_t u32;
typedef __attribute__((ext_vector_type(8))) short bf16x8;
typedef __attribute__((ext_vector_type(4))) float f32x4;
typedef __attribute__((ext_vector_type(4))) u32 u32x4;
typedef __attribute__((ext_vector_type(2))) u32 u32x2;

__device__ __forceinline__ unsigned short f2bf(float f) {
  u32 u = __builtin_bit_cast(u32, f);
  u32 r = (u + 0x7FFFu + ((u >> 16) & 1u)) >> 16;   // RNE
  return (unsigned short)r;
}

// ------------------------------------------------------------------
// Kernel 0: weight re-layouts (tiny).
//  wct[c][cc] = w_comp[cc][c]
//  wfrag[ks(50)][mt(14)][lane(64)][j(8)] bf16 fragment-linear A operand
// ------------------------------------------------------------------
__global__ __launch_bounds__(256) void prep_weights(
    const float* __restrict__ w_comp, const float* __restrict__ w_enc,
    float* __restrict__ wct, unsigned short* __restrict__ wfrag) {
  int idx = blockIdx.x * 256 + threadIdx.x;
  if (idx < 50 * 14 * 64) {
    int lane = idx & 63;
    int mt   = (idx >> 6) % 14;
    int ks   = idx / (14 * 64);
    int o    = mt * 16 + (lane & 15);
    int tap  = ks >> 1, s = ks & 1;
    int ky   = tap / 5, kx = tap % 5;
    int cb   = s * 32 + (lane >> 4) * 8;
    u32 pk[4];
    #pragma unroll
    for (int p = 0; p < 4; ++p) {
      unsigned short lo = 0, hi = 0;
      if (o < OE_) {
        lo = f2bf(w_enc[((o * CC_ + cb + 2 * p) * 5 + ky) * 5 + kx]);
        hi = f2bf(w_enc[((o * CC_ + cb + 2 * p + 1) * 5 + ky) * 5 + kx]);
      }
      pk[p] = (u32)lo | ((u32)hi << 16);
    }
    *reinterpret_cast<u32x4*>(wfrag + (size_t)idx * 8) =
        *reinterpret_cast<u32x4*>(pk);
  }
  if (idx < C_ * CC_) {
    int cc = idx / C_, c = idx % C_;
    wct[c * CC_ + cc] = w_comp[cc * C_ + c];
  }
}

// ------------------------------------------------------------------
// Kernel 1: 1x1 compressor — 16-w blocks, grid 1024, LDS 20KB.
// ------------------------------------------------------------------
__global__ __launch_bounds__(256) void compress_k(
    const float* __restrict__ x, const float* __restrict__ wct,
    const float* __restrict__ b_comp, unsigned short* __restrict__ comp) {
  __shared__ float xs[C_ * 20];   // 20,480B
  int t   = threadIdx.x;
  int gid = blockIdx.x;           // bh*4 + wq
  int wq  = gid & 3;
  int bh  = gid >> 2;
  int b = bh >> 6, h = bh & 63;
  int w0 = wq * 16;

  const float* xrow = x + (size_t)b * C_ * H_ * W_ + (size_t)h * W_ + w0;
  for (int i = t; i < 1024; i += 256) {    // 256 c x 4 f32x4
    int c = i >> 2, q = i & 3;
    f32x4 v = *reinterpret_cast<const f32x4*>(xrow + (size_t)c * H_ * W_ + q * 4);
    *reinterpret_cast<f32x4*>(xs + c * 20 + q * 4) = v;
  }
  __syncthreads();

  int w = t & 15, cq = t >> 4;   // cq 0..15 -> 4 cc each
  float acc[4] = {0.f, 0.f, 0.f, 0.f};
  for (int c = 0; c < C_; ++c) {
    float xv = xs[c * 20 + w];
    const float* wr = wct + c * CC_ + cq * 4;
    #pragma unroll
    for (int i = 0; i < 4; ++i) acc[i] = fmaf(xv, wr[i], acc[i]);
  }
  u32 pk[2];
  #pragma unroll
  for (int p = 0; p < 2; ++p) {
    unsigned short lo = f2bf(acc[2 * p]     + b_comp[cq * 4 + 2 * p]);
    unsigned short hi = f2bf(acc[2 * p + 1] + b_comp[cq * 4 + 2 * p + 1]);
    pk[p] = (u32)lo | ((u32)hi << 16);
  }
  *reinterpret_cast<u32x2*>(comp + ((size_t)bh * 64 + w0 + w) * CC_ + cq * 4) =
      *reinterpret_cast<u32x2*>(pk);
}

// ------------------------------------------------------------------
// Kernel 2: encoder MFMA GEMM v3 — BARRIER-FREE K-loop.
// A operand: straight from global (L2/L3-resident wfrag, coalesced
// 1KB/wave loads) with 2-deep ping-pong register prefetch.  No wbuf,
// no per-ks __syncthreads.  B tile in LDS (read-only after 1 sync).
// ------------------------------------------------------------------
#define CSB_ 43520
#define LGB_ 60928   // 224*68*4 logits scratch (reuses same LDS)

__device__ __forceinline__ void enc_lda(
    bf16x8 (&a)[4], const unsigned short* __restrict__ wfrag,
    int ks, int mtbase, int mtcnt, int lane) {
  #pragma unroll
  for (int mm = 0; mm < 4; ++mm)
    if (mm < mtcnt)
      a[mm] = *reinterpret_cast<const bf16x8*>(
          wfrag + (((size_t)ks * 14 + mtbase + mm) * 64 + lane) * 8);
}

__device__ __forceinline__ void enc_step(
    int ks, const char* lds, const bf16x8 (&a)[4], f32x4 (&acc)[4][4],
    int nlane, int kq, int mtcnt) {
  int tap = ks >> 1, s = ks & 1;
  int ky = tap / 5, kx = tap % 5;
  bf16x8 bf[4];
  #pragma unroll
  for (int nt = 0; nt < 4; ++nt) {
    int col = nt * 16 + nlane + kx;
    int byte = (((ky * 68 + col) * 64 + s * 32 + kq * 8) * 2) ^ ((col & 7) << 4);
    bf[nt] = *reinterpret_cast<const bf16x8*>(lds + byte);
  }
  #pragma unroll
  for (int mm = 0; mm < 4; ++mm) {
    if (mm < mtcnt) {
      #pragma unroll
      for (int nt = 0; nt < 4; ++nt)
        acc[mm][nt] = __builtin_amdgcn_mfma_f32_16x16x32_bf16(
            a[mm], bf[nt], acc[mm][nt], 0, 0, 0);
    }
  }
}

__global__ __launch_bounds__(256) void enc_mfma_k(
    const unsigned short* __restrict__ comp,
    const unsigned short* __restrict__ wfrag,
    const float* __restrict__ b_enc,
    float* __restrict__ smax) {
  __shared__ __align__(16) char lds[LGB_];   // 60,928 B

  int t = threadIdx.x;
  int bh = blockIdx.x;
  int b = bh >> 6, h = bh & 63;

  // ---- stage B tile (rows h-2..h+2, cols 0..67, XOR-swizzled) ----
  {
    u32x4 z = {0, 0, 0, 0};
    for (int i = t; i < 160; i += 256) {
      int r = i / 32, rem = i & 31, ch = rem >> 3, q = rem & 7;
      int col = (ch < 2) ? ch : 64 + ch;
      int byte = ((r * 68 + col) * 128 + q * 16) ^ ((col & 7) << 4);
      *reinterpret_cast<u32x4*>(lds + byte) = z;
    }
    const unsigned short* cbse = comp + (size_t)b * H_ * W_ * CC_;
    for (int i = t; i < 2560; i += 256) {
      int r = i >> 9, rem = i & 511, w = rem >> 3, q = rem & 7;
      int hh = h - 2 + r;
      u32x4 v = {0, 0, 0, 0};
      if ((unsigned)hh < H_)
        v = *reinterpret_cast<const u32x4*>(cbse + ((size_t)hh * W_ + w) * CC_ + q * 8);
      int col = w + 2;
      int byte = ((r * 68 + col) * 128 + q * 16) ^ ((col & 7) << 4);
      *reinterpret_cast<u32x4*>(lds + byte) = v;
    }
  }
  __syncthreads();   // B tile ready; no further barriers in K-loop

  int wv    = __builtin_amdgcn_readfirstlane(t >> 6);
  int lane  = t & 63;
  int nlane = lane & 15, kq = lane >> 4;
  int mtbase = (wv < 2) ? wv * 4 : 3 * wv + 2;   // {0,4,8,11}
  int mtcnt  = (wv < 2) ? 4 : 3;

  f32x4 acc[4][4];
  #pragma unroll
  for (int mm = 0; mm < 4; ++mm)
    #pragma unroll
    for (int nt = 0; nt < 4; ++nt) acc[mm][nt] = (f32x4){0.f, 0.f, 0.f, 0.f};

  bf16x8 aA[4], aB[4];
  enc_lda(aA, wfrag, 0, mtbase, mtcnt, lane);
  enc_lda(aB, wfrag, 1, mtbase, mtcnt, lane);
  for (int ks = 0; ks + 2 < 50; ks += 2) {
    enc_step(ks, lds, aA, acc, nlane, kq, mtcnt);
    enc_lda(aA, wfrag, ks + 2, mtbase, mtcnt, lane);
    enc_step(ks + 1, lds, aB, acc, nlane, kq, mtcnt);
    enc_lda(aB, wfrag, ks + 3, mtbase, mtcnt, lane);   // ks<=46 -> ks+3<=49
  }
  enc_step(48, lds, aA, acc, nlane, kq, mtcnt);
  enc_step(49, lds, aB, acc, nlane, kq, mtcnt);

  // ---- epilogue: logits -> LDS [224][68] f32, then softmax ----
  __syncthreads();   // all waves done reading B tile
  float* lg = (float*)lds;
  #pragma unroll
  for (int mm = 0; mm < 4; ++mm) {
    if (mm < mtcnt) {
      #pragma unroll
      for (int nt = 0; nt < 4; ++nt) {
        #pragma unroll
        for (int r = 0; r < 4; ++r) {
          int m  = (mtbase + mm) * 16 + kq * 4 + r;
          int px = nt * 16 + nlane;
          lg[m * 68 + px] = acc[mm][nt][r] + (m < OE_ ? b_enc[m] : 0.f);
        }
      }
    }
  }
  __syncthreads();

  int px = t & 63, rr = t >> 6;
  float v[49];
  float mx = -1e30f;
  #pragma unroll
  for (int n = 0; n < 49; ++n) {
    v[n] = lg[(4 * n + rr) * 68 + px];
    mx = fmaxf(mx, v[n]);
  }
  float sum = 0.f;
  #pragma unroll
  for (int n = 0; n < 49; ++n) { v[n] = __expf(v[n] - mx); sum += v[n]; }
  float inv = 1.f / sum;
  float* so = smax + ((size_t)bh * 64 + px) * OE_;
  #pragma unroll
  for (int n = 0; n < 49; ++n) so[n * 4 + rr] = v[n] * inv;   // [n][r] layout
}

// ------------------------------------------------------------------
// Kernel 3: CARAFE v7 — R4 structure (proven 0-conflict reads, no
// spills) + XCD swizzle + direct-from-x staging (no xt buffer).
// 32ch x 32w blocks, xs[dy][38 j][36 c] channels-last, LDS 38.3KB.
// Per tap: 1 global b128 (sv) + 1 LDS b128 (xv, 4ch) + 16 FMA.
// ------------------------------------------------------------------
__global__ __launch_bounds__(256) void carafe_k(
    const float* __restrict__ x, const float* __restrict__ smax,
    float* __restrict__ out) {
  __shared__ __align__(16) float xs[7 * 38 * 36];   // 38,304 B
  int t   = threadIdx.x;
  int bid = blockIdx.x;
  int swz = (bid & 7) * 512 + (bid >> 3);   // 4096 blocks, bijective XCD chunk
  int cg  = swz & 7;
  int wh  = (swz >> 3) & 1;
  int bh  = swz >> 4;
  int b = bh >> 6, h = bh & 63;
  int c0 = cg * 32, w0 = wh * 32;

  // ---- stage x tile with transpose: 32c x 7dy x 10 vec4 reads ----
  const float* xb = x + (size_t)(b * C_ + c0) * H_ * W_;
  for (int idx = t; idx < 2240; idx += 256) {
    int c = idx / 70, rem = idx % 70;
    int dy = rem / 10, q = rem - dy * 10;
    int gh = h - 3 + dy;
    int gw0 = w0 - 4 + q * 4;                  // 4-aligned
    f32x4 v = {0.f, 0.f, 0.f, 0.f};
    if ((unsigned)gh < H_ && (unsigned)gw0 < 61)
      v = *reinterpret_cast<const f32x4*>(xb + (size_t)c * H_ * W_ + gh * W_ + gw0);
    int jb = 4 * q - 1;                        // j = gw - (w0-3)
    #pragma unroll
    for (int e = 0; e < 4; ++e) {
      int j = jb + e;
      if ((unsigned)j < 38) xs[(dy * 38 + j) * 36 + c] = v[e];
    }
  }
  __syncthreads();

  int w = t & 31;
  int coff = (t >> 5) * 4;                     // 8 groups x 4 channels
  const float* sp = smax + ((size_t)bh * 64 + w0 + w) * OE_;
  f32x4 acc[4];
  #pragma unroll
  for (int ci = 0; ci < 4; ++ci) acc[ci] = (f32x4){0.f, 0.f, 0.f, 0.f};

  #pragma unroll
  for (int dy = 0; dy < 7; ++dy) {
    #pragma unroll
    for (int dx = 0; dx < 7; ++dx) {
      int n = dy * 7 + dx;
      f32x4 sv = *reinterpret_cast<const f32x4*>(sp + n * 4);
      f32x4 xv = *reinterpret_cast<const f32x4*>(
          xs + (dy * 38 + w + dx) * 36 + coff);
      #pragma unroll
      for (int ci = 0; ci < 4; ++ci) {
        acc[ci][0] = fmaf(xv[ci], sv[0], acc[ci][0]);
        acc[ci][1] = fmaf(xv[ci], sv[1], acc[ci][1]);
        acc[ci][2] = fmaf(xv[ci], sv[2], acc[ci][2]);
        acc[ci][3] = fmaf(xv[ci], sv[3], acc[ci][3]);
      }
    }
  }
  #pragma unroll
  for (int ci = 0; ci < 4; ++ci) {
    int c = c0 + coff + ci;
    float* base = out + ((size_t)(b * C_ + c) * OH_ + 2 * h) * OW_ + 2 * (w0 + w);
    *reinterpret_cast<float2*>(base)       = make_float2(acc[ci][0], acc[ci][1]);
    *reinterpret_cast<float2*>(base + OW_) = make_float2(acc[ci][2], acc[ci][3]);
  }
}

// ------------------------------------------------------------------
extern "C" void kernel_launch(void* const* d_in, const int* in_sizes, int n_in,
                              void* d_out, int out_size, void* d_ws, size_t ws_size,
                              hipStream_t stream) {
  const float* x      = (const float*)d_in[0];
  const float* w_comp = (const float*)d_in[1];
  const float* b_comp = (const float*)d_in[2];
  const float* w_enc  = (const float*)d_in[3];
  const float* b_enc  = (const float*)d_in[4];
  float* out = (float*)d_out;

  float* ws = (float*)d_ws;
  float* smax = ws;                                        // 3,211,264 f32
  float* wct  = ws + 3211264;                              //    16,384 f32
  unsigned short* wfrag = (unsigned short*)(wct + 16384);  //   358,400 bf16
  unsigned short* comp  = wfrag + 358400;                  // 1,048,576 bf16

  prep_weights<<<175, 256, 0, stream>>>(w_comp, w_enc, wct, wfrag);
  compress_k<<<B_ * H_ * 4, 256, 0, stream>>>(x, wct, b_comp, comp);
  enc_mfma_k<<<B_ * H_, 256, 0, stream>>>(comp, wfrag, b_enc, smax);
  carafe_k<<<B_ * H_ * 2 * 8, 256, 0, stream>>>(x, smax, out);
}

// Round 8
// 147.266 us; speedup vs baseline: 1.4006x; 1.0620x over previous
//
#include <hip/hip_runtime.h>
#include <math.h>
#include <stdint.h>

#define B_   4
#define C_   256
#define H_   64
#define W_   64
#define CC_  64
#define OE_  196
#define OH_  128
#define OW_  128

typedef uint32_t u32;
typedef unsigned short u16;
typedef __attribute__((ext_vector_type(8))) short bf16x8;
typedef __attribute__((ext_vector_type(4))) float f32x4;
typedef __attribute__((ext_vector_type(4))) u32 u32x4;
typedef __attribute__((ext_vector_type(2))) u32 u32x2;

__device__ __forceinline__ u16 f2bf(float f) {
  u32 u = __builtin_bit_cast(u32, f);
  u32 r = (u + 0x7FFFu + ((u >> 16) & 1u)) >> 16;   // RNE
  return (u16)r;
}

// ------------------------------------------------------------------
// Kernel 0: weight re-layouts (tiny).
//  wct[c][cc] = w_comp[cc][c]
//  wfrag[ks(50)][mt(14)][lane(64)][j(8)] bf16 fragment-linear A operand
// ------------------------------------------------------------------
__global__ __launch_bounds__(256) void prep_weights(
    const float* __restrict__ w_comp, const float* __restrict__ w_enc,
    float* __restrict__ wct, u16* __restrict__ wfrag) {
  int idx = blockIdx.x * 256 + threadIdx.x;
  if (idx < 50 * 14 * 64) {
    int lane = idx & 63;
    int mt   = (idx >> 6) % 14;
    int ks   = idx / (14 * 64);
    int o    = mt * 16 + (lane & 15);
    int tap  = ks >> 1, s = ks & 1;
    int ky   = tap / 5, kx = tap % 5;
    int cb   = s * 32 + (lane >> 4) * 8;
    u32 pk[4];
    #pragma unroll
    for (int p = 0; p < 4; ++p) {
      u16 lo = 0, hi = 0;
      if (o < OE_) {
        lo = f2bf(w_enc[((o * CC_ + cb + 2 * p) * 5 + ky) * 5 + kx]);
        hi = f2bf(w_enc[((o * CC_ + cb + 2 * p + 1) * 5 + ky) * 5 + kx]);
      }
      pk[p] = (u32)lo | ((u32)hi << 16);
    }
    *reinterpret_cast<u32x4*>(wfrag + (size_t)idx * 8) =
        *reinterpret_cast<u32x4*>(pk);
  }
  if (idx < C_ * CC_) {
    int cc = idx / C_, c = idx % C_;
    wct[c * CC_ + cc] = w_comp[cc * C_ + c];
  }
}

// ------------------------------------------------------------------
// Kernel 1: 1x1 compressor — 16-w blocks, grid 1024, LDS 20KB.
// ------------------------------------------------------------------
__global__ __launch_bounds__(256) void compress_k(
    const float* __restrict__ x, const float* __restrict__ wct,
    const float* __restrict__ b_comp, u16* __restrict__ comp) {
  __shared__ float xs[C_ * 20];   // 20,480B
  int t   = threadIdx.x;
  int gid = blockIdx.x;           // bh*4 + wq
  int wq  = gid & 3;
  int bh  = gid >> 2;
  int b = bh >> 6, h = bh & 63;
  int w0 = wq * 16;

  const float* xrow = x + (size_t)b * C_ * H_ * W_ + (size_t)h * W_ + w0;
  for (int i = t; i < 1024; i += 256) {    // 256 c x 4 f32x4
    int c = i >> 2, q = i & 3;
    f32x4 v = *reinterpret_cast<const f32x4*>(xrow + (size_t)c * H_ * W_ + q * 4);
    *reinterpret_cast<f32x4*>(xs + c * 20 + q * 4) = v;
  }
  __syncthreads();

  int w = t & 15, cq = t >> 4;   // cq 0..15 -> 4 cc each
  float acc[4] = {0.f, 0.f, 0.f, 0.f};
  for (int c = 0; c < C_; ++c) {
    float xv = xs[c * 20 + w];
    const float* wr = wct + c * CC_ + cq * 4;
    #pragma unroll
    for (int i = 0; i < 4; ++i) acc[i] = fmaf(xv, wr[i], acc[i]);
  }
  u32 pk[2];
  #pragma unroll
  for (int p = 0; p < 2; ++p) {
    u16 lo = f2bf(acc[2 * p]     + b_comp[cq * 4 + 2 * p]);
    u16 hi = f2bf(acc[2 * p + 1] + b_comp[cq * 4 + 2 * p + 1]);
    pk[p] = (u32)lo | ((u32)hi << 16);
  }
  *reinterpret_cast<u32x2*>(comp + ((size_t)bh * 64 + w0 + w) * CC_ + cq * 4) =
      *reinterpret_cast<u32x2*>(pk);
}

// ------------------------------------------------------------------
// Kernel 2: encoder MFMA GEMM v5 — N-SPLIT for occupancy.
// Block = (b, h, w-half): M=224, N=32, K=1600.  Grid 512 (+XCD swz).
// LDS 32.25KB (B-tile 23KB then logits 32.25KB, same buffer)
//   -> 4 blocks/CU, 16 waves/CU (50%).  Fused softmax kept (full M).
// A operand: global 2-deep ping-pong (wfrag L2-resident). No K-loop
// barriers.
// ------------------------------------------------------------------
#define ELG_ 32256   // 224*36*4

__device__ __forceinline__ void enc_lda(
    bf16x8 (&a)[4], const u16* __restrict__ wfrag,
    int ks, int mtbase, int mtcnt, int lane) {
  #pragma unroll
  for (int mm = 0; mm < 4; ++mm)
    if (mm < mtcnt)
      a[mm] = *reinterpret_cast<const bf16x8*>(
          wfrag + (((size_t)ks * 14 + mtbase + mm) * 64 + lane) * 8);
}

__device__ __forceinline__ void enc_step(
    int ks, const char* lds, const bf16x8 (&a)[4], f32x4 (&acc)[4][2],
    int nlane, int kq, int mtcnt) {
  int tap = ks >> 1, s = ks & 1;
  int ky = tap / 5, kx = tap % 5;
  bf16x8 bf[2];
  #pragma unroll
  for (int nt = 0; nt < 2; ++nt) {
    int col = nt * 16 + nlane + kx;
    int byte = (((ky * 36 + col) * 64 + s * 32 + kq * 8) * 2) ^ ((col & 7) << 4);
    bf[nt] = *reinterpret_cast<const bf16x8*>(lds + byte);
  }
  #pragma unroll
  for (int mm = 0; mm < 4; ++mm) {
    if (mm < mtcnt) {
      #pragma unroll
      for (int nt = 0; nt < 2; ++nt)
        acc[mm][nt] = __builtin_amdgcn_mfma_f32_16x16x32_bf16(
            a[mm], bf[nt], acc[mm][nt], 0, 0, 0);
    }
  }
}

__global__ __launch_bounds__(256) void enc_mfma_k(
    const u16* __restrict__ comp, const u16* __restrict__ wfrag,
    const float* __restrict__ b_enc, float* __restrict__ smax) {
  __shared__ __align__(16) char lds[ELG_];

  int t   = threadIdx.x;
  int bid = blockIdx.x;
  int swz = (bid & 7) * 64 + (bid >> 3);   // 512 blocks, bijective
  int wh  = swz & 1;
  int bh  = swz >> 1;
  int b = bh >> 6, h = bh & 63;
  int w0 = wh * 32;

  // ---- stage B tile: 5 rows x 36 cols (gw = w0-2+col) x 64 ch ----
  {
    const u16* cbse = comp + (size_t)b * H_ * W_ * CC_;
    for (int i = t; i < 1440; i += 256) {
      int q = i & 7, colr = i >> 3;
      int col = colr % 36, r = colr / 36;
      int hh = h - 2 + r, gw = w0 - 2 + col;
      u32x4 v = {0, 0, 0, 0};
      if ((unsigned)hh < H_ && (unsigned)gw < W_)
        v = *reinterpret_cast<const u32x4*>(cbse + ((size_t)hh * W_ + gw) * CC_ + q * 8);
      int byte = ((r * 36 + col) * 128 + q * 16) ^ ((col & 7) << 4);
      *reinterpret_cast<u32x4*>(lds + byte) = v;
    }
  }
  __syncthreads();   // B ready; no further barriers in K-loop

  int wv    = __builtin_amdgcn_readfirstlane(t >> 6);
  int lane  = t & 63;
  int nlane = lane & 15, kq = lane >> 4;
  int mtbase = (wv < 2) ? wv * 4 : 3 * wv + 2;   // {0,4,8,11}
  int mtcnt  = (wv < 2) ? 4 : 3;

  f32x4 acc[4][2];
  #pragma unroll
  for (int mm = 0; mm < 4; ++mm)
    #pragma unroll
    for (int nt = 0; nt < 2; ++nt) acc[mm][nt] = (f32x4){0.f, 0.f, 0.f, 0.f};

  bf16x8 aA[4], aB[4];
  enc_lda(aA, wfrag, 0, mtbase, mtcnt, lane);
  enc_lda(aB, wfrag, 1, mtbase, mtcnt, lane);
  for (int ks = 0; ks + 2 < 50; ks += 2) {
    enc_step(ks, lds, aA, acc, nlane, kq, mtcnt);
    enc_lda(aA, wfrag, ks + 2, mtbase, mtcnt, lane);
    enc_step(ks + 1, lds, aB, acc, nlane, kq, mtcnt);
    enc_lda(aB, wfrag, ks + 3, mtbase, mtcnt, lane);
  }
  enc_step(48, lds, aA, acc, nlane, kq, mtcnt);
  enc_step(49, lds, aB, acc, nlane, kq, mtcnt);

  // ---- epilogue: logits -> LDS [224][36] f32, fused softmax ----
  __syncthreads();
  float* lg = (float*)lds;
  #pragma unroll
  for (int mm = 0; mm < 4; ++mm) {
    if (mm < mtcnt) {
      #pragma unroll
      for (int nt = 0; nt < 2; ++nt) {
        #pragma unroll
        for (int r = 0; r < 4; ++r) {
          int m  = (mtbase + mm) * 16 + kq * 4 + r;
          int px = nt * 16 + nlane;
          lg[m * 36 + px] = acc[mm][nt][r] + (m < OE_ ? b_enc[m] : 0.f);
        }
      }
    }
  }
  __syncthreads();

  if (t < 128) {
    int px = t & 31, rr = t >> 5;   // rr 0..3
    float v[49];
    float mx = -1e30f;
    #pragma unroll
    for (int n = 0; n < 49; ++n) {
      v[n] = lg[(4 * n + rr) * 36 + px];
      mx = fmaxf(mx, v[n]);
    }
    float sum = 0.f;
    #pragma unroll
    for (int n = 0; n < 49; ++n) { v[n] = __expf(v[n] - mx); sum += v[n]; }
    float inv = 1.f / sum;
    float* so = smax + ((size_t)bh * 64 + w0 + px) * OE_;
    #pragma unroll
    for (int n = 0; n < 49; ++n) so[n * 4 + rr] = v[n] * inv;   // [n][r]
  }
}

// ------------------------------------------------------------------
// Kernel 3: CARAFE v8 — R4-proven conflict-free layout, direct-x
// staging via 4-scalar-gather + ONE b128 LDS write per thread
// (bank group 4(j+cq)%32: <=2-way = free).  sv from global (swizzled
// L2), dy=0's 7 sv preloaded BEFORE the barrier to overlap staging.
// ------------------------------------------------------------------
__global__ __launch_bounds__(256) void carafe_k(
    const float* __restrict__ x, const float* __restrict__ smax,
    float* __restrict__ out) {
  __shared__ __align__(16) float xs[7 * 38 * 36];   // 38,304 B
  int t   = threadIdx.x;
  int bid = blockIdx.x;
  int swz = (bid & 7) * 512 + (bid >> 3);   // 4096 blocks, bijective
  int cg  = swz & 7;
  int wh  = (swz >> 3) & 1;
  int bh  = swz >> 4;
  int b = bh >> 6, h = bh & 63;
  int c0 = cg * 32, w0 = wh * 32;

  int w = t & 31;
  int coff = (t >> 5) * 4;
  const float* sp = smax + ((size_t)bh * 64 + w0 + w) * OE_;

  // preload dy=0 sv (independent of LDS -> overlaps staging)
  f32x4 pre0 = *reinterpret_cast<const f32x4*>(sp + 0);
  f32x4 pre1 = *reinterpret_cast<const f32x4*>(sp + 4);
  f32x4 pre2 = *reinterpret_cast<const f32x4*>(sp + 8);
  f32x4 pre3 = *reinterpret_cast<const f32x4*>(sp + 12);
  f32x4 pre4 = *reinterpret_cast<const f32x4*>(sp + 16);
  f32x4 pre5 = *reinterpret_cast<const f32x4*>(sp + 20);
  f32x4 pre6 = *reinterpret_cast<const f32x4*>(sp + 24);

  // ---- stage x tile: thread = (dy, j, cq): 4 scalar loads + 1 b128 write
  const float* xb = x + (size_t)(b * C_ + c0) * H_ * W_;
  for (int idx = t; idx < 2128; idx += 256) {
    int cq = idx & 7, rj = idx >> 3;       // rj = dy*38 + j
    int dy = rj / 38, j = rj - dy * 38;
    int gh = h - 3 + dy, gw = w0 - 3 + j;
    f32x4 v = {0.f, 0.f, 0.f, 0.f};
    if ((unsigned)gh < H_ && (unsigned)gw < W_) {
      const float* xp = xb + (size_t)(cq * 4) * H_ * W_ + gh * W_ + gw;
      v[0] = xp[0];
      v[1] = xp[H_ * W_];
      v[2] = xp[2 * H_ * W_];
      v[3] = xp[3 * H_ * W_];
    }
    *reinterpret_cast<f32x4*>(xs + rj * 36 + cq * 4) = v;
  }
  __syncthreads();

  f32x4 acc[4];
  #pragma unroll
  for (int ci = 0; ci < 4; ++ci) acc[ci] = (f32x4){0.f, 0.f, 0.f, 0.f};

  #pragma unroll
  for (int dy = 0; dy < 7; ++dy) {
    #pragma unroll
    for (int dx = 0; dx < 7; ++dx) {
      f32x4 sv;
      if (dy == 0) {
        sv = (dx == 0) ? pre0 : (dx == 1) ? pre1 : (dx == 2) ? pre2 :
             (dx == 3) ? pre3 : (dx == 4) ? pre4 : (dx == 5) ? pre5 : pre6;
      } else {
        sv = *reinterpret_cast<const f32x4*>(sp + (dy * 7 + dx) * 4);
      }
      f32x4 xv = *reinterpret_cast<const f32x4*>(
          xs + (dy * 38 + w + dx) * 36 + coff);
      #pragma unroll
      for (int ci = 0; ci < 4; ++ci) {
        acc[ci][0] = fmaf(xv[ci], sv[0], acc[ci][0]);
        acc[ci][1] = fmaf(xv[ci], sv[1], acc[ci][1]);
        acc[ci][2] = fmaf(xv[ci], sv[2], acc[ci][2]);
        acc[ci][3] = fmaf(xv[ci], sv[3], acc[ci][3]);
      }
    }
  }
  #pragma unroll
  for (int ci = 0; ci < 4; ++ci) {
    int c = c0 + coff + ci;
    float* base = out + ((size_t)(b * C_ + c) * OH_ + 2 * h) * OW_ + 2 * (w0 + w);
    *reinterpret_cast<float2*>(base)       = make_float2(acc[ci][0], acc[ci][1]);
    *reinterpret_cast<float2*>(base + OW_) = make_float2(acc[ci][2], acc[ci][3]);
  }
}

// ------------------------------------------------------------------
extern "C" void kernel_launch(void* const* d_in, const int* in_sizes, int n_in,
                              void* d_out, int out_size, void* d_ws, size_t ws_size,
                              hipStream_t stream) {
  const float* x      = (const float*)d_in[0];
  const float* w_comp = (const float*)d_in[1];
  const float* b_comp = (const float*)d_in[2];
  const float* w_enc  = (const float*)d_in[3];
  const float* b_enc  = (const float*)d_in[4];
  float* out = (float*)d_out;

  float* ws = (float*)d_ws;
  float* smax = ws;                             // 3,211,264 f32
  float* wct  = ws + 3211264;                   //    16,384 f32
  u16* wfrag  = (u16*)(wct + 16384);            //   358,400 bf16
  u16* comp   = wfrag + 358400;                 // 1,048,576 bf16

  prep_weights<<<175, 256, 0, stream>>>(w_comp, w_enc, wct, wfrag);
  compress_k<<<B_ * H_ * 4, 256, 0, stream>>>(x, wct, b_comp, comp);
  enc_mfma_k<<<512, 256, 0, stream>>>(comp, wfrag, b_enc, smax);
  carafe_k<<<B_ * H_ * 2 * 8, 256, 0, stream>>>(x, smax, out);
}